// Round 16
// baseline (3210.630 us; speedup 1.0000x reference)
//
#include <hip/hip_runtime.h>
#include <hip/hip_fp16.h>

#define TPB 256

typedef _Float16 f16;
typedef __attribute__((ext_vector_type(8))) _Float16 f16x8;
typedef __attribute__((ext_vector_type(4))) float f32x4;

// ---------------- one-time transposes ----------------
__global__ void k_prep_hw1(const float* __restrict__ hw1, f16* __restrict__ hw1T) {
  int idx = blockIdx.x * TPB + threadIdx.x;
  if (idx >= 4096 * 64) return;
  int z = idx & 63, n = idx >> 6;
  hw1T[idx] = (f16)hw1[z * 4096 + n];
}

__global__ void k_prep_hw2(const float* __restrict__ hw2, const float* __restrict__ hb2,
                           f16* __restrict__ hw2T, float* __restrict__ b2T,
                           float* __restrict__ stz, float* __restrict__ mvxz) {
  int idx = blockIdx.x * TPB + threadIdx.x;
  if (idx < 128) stz[idx] = 0.f;
  if (idx < 8) mvxz[idx] = 0.f;
  if (idx >= 576 * 64) return;
  int z = idx & 63, j = idx >> 6;
  int tap = j >> 6, c = j & 63;
  hw2T[(size_t)j * 64 + z] = (f16)hw2[z * 576 + c * 9 + tap];
  if (z == 0) b2T[j] = hb2[c * 9 + tap];
}

// stem weights: conv B^T layout [tap][co=64][ci=64], 10th tap zero pad
__global__ void k_prep_stemw(const float* __restrict__ w, f16* __restrict__ sw) {
  int idx = blockIdx.x * TPB + threadIdx.x;
  if (idx >= 10 * 64 * 64) return;
  int ci = idx & 63, co = (idx >> 6) & 63, tap = idx >> 12;
  float v = 0.f;
  if (tap < 9 && ci < 3) v = w[co * 27 + ci * 9 + tap];
  sw[idx] = (f16)v;
}

// ---------------- gen_h: h[3268 x 4096] = z @ hw1T^T + hb1 (MFMA) ----------------
__global__ __launch_bounds__(256) void k_gen_h_mfma(
    const float* __restrict__ z, const f16* __restrict__ hw1T, const float* __restrict__ hb1,
    f16* __restrict__ h, int M) {
  __shared__ f16 As[256 * 64];
  __shared__ f16 Bs[64 * 64];
  const int t = threadIdx.x, lane = t & 63, wid = t >> 6;
  const int m0 = blockIdx.x * 256;
  const int n0 = blockIdx.y * 64;
  char* AsB = (char*)As;
  char* BsB = (char*)Bs;
  {
    int row = t;
    bool ok = (m0 + row) < M;
    const float* src = z + (size_t)(m0 + row) * 64;
#pragma unroll
    for (int ch = 0; ch < 8; ch++) {
      f16x8 v = {};
      if (ok) {
        f32x4 a = *(const f32x4*)(src + ch * 8);
        f32x4 b = *(const f32x4*)(src + ch * 8 + 4);
#pragma unroll
        for (int q = 0; q < 4; q++) { v[q] = (f16)a[q]; v[q + 4] = (f16)b[q]; }
      }
      *(f16x8*)(AsB + row * 128 + ((ch ^ (row & 7)) << 4)) = v;
    }
  }
  {
#pragma unroll
    for (int q = 0; q < 2; q++) {
      int id = t + q * 256;
      int row = id >> 3, ch = id & 7;
      f16x8 v = *(const f16x8*)(hw1T + ((size_t)(n0 + row)) * 64 + ch * 8);
      *(f16x8*)(BsB + row * 128 + ((ch ^ (row & 7)) << 4)) = v;
    }
  }
  __syncthreads();
  f32x4 acc[4][4];
#pragma unroll
  for (int m = 0; m < 4; m++)
#pragma unroll
    for (int n = 0; n < 4; n++) acc[m][n] = (f32x4){0.f, 0.f, 0.f, 0.f};
#pragma unroll
  for (int ks = 0; ks < 2; ks++) {
    f16x8 af[4], bf[4];
#pragma unroll
    for (int m = 0; m < 4; m++) {
      int row = wid * 64 + m * 16 + (lane & 15);
      int c = ks * 4 + (lane >> 4);
      af[m] = *(const f16x8*)(AsB + row * 128 + ((c ^ (row & 7)) << 4));
    }
#pragma unroll
    for (int n = 0; n < 4; n++) {
      int row = n * 16 + (lane & 15);
      int c = ks * 4 + (lane >> 4);
      bf[n] = *(const f16x8*)(BsB + row * 128 + ((c ^ (row & 7)) << 4));
    }
#pragma unroll
    for (int m = 0; m < 4; m++)
#pragma unroll
      for (int n = 0; n < 4; n++)
        acc[m][n] = __builtin_amdgcn_mfma_f32_16x16x32_f16(af[m], bf[n], acc[m][n], 0, 0, 0);
  }
#pragma unroll
  for (int n = 0; n < 4; n++) {
    int c = n * 16 + (lane & 15);
    float bj = hb1[n0 + c];
#pragma unroll
    for (int m = 0; m < 4; m++) {
      int rbase = m0 + wid * 64 + m * 16 + (lane >> 4) * 4;
#pragma unroll
      for (int r = 0; r < 4; r++) {
        int row = rbase + r;
        if (row < M) h[(size_t)row * 4096 + n0 + c] = (f16)(acc[m][n][r] + bj);
      }
    }
  }
}

// ---------------- gen_w: scatter into w[tap][co][ci]; block0 zeroes upcoming stats ----------------
__global__ __launch_bounds__(256) void k_gen_w(
    const f16* __restrict__ h, const f16* __restrict__ hw2T, const float* __restrict__ b2T,
    f16* __restrict__ wout, int hoff, int M, int l2kk, int Cin, int Cout,
    float* __restrict__ st, int stClr) {
  __shared__ f16 As[256 * 64];
  __shared__ f16 Bs[64 * 64];
  const int t = threadIdx.x, lane = t & 63, wid = t >> 6;
  const int m0 = blockIdx.x * 256;
  const int tap = blockIdx.y;
  char* AsB = (char*)As;
  char* BsB = (char*)Bs;
  if (blockIdx.x == 0 && blockIdx.y == 0)
    for (int i = t; i < stClr; i += 256) st[i] = 0.f;
  {
    int row = t;
    const f16* src = h + (size_t)(hoff + m0 + row) * 64;
    bool ok = (m0 + row) < M;
#pragma unroll
    for (int ch = 0; ch < 8; ch++) {
      f16x8 v = {};
      if (ok) v = *(const f16x8*)(src + ch * 8);
      *(f16x8*)(AsB + row * 128 + ((ch ^ (row & 7)) << 4)) = v;
    }
  }
  {
#pragma unroll
    for (int q = 0; q < 2; q++) {
      int id = t + q * 256;
      int row = id >> 3, ch = id & 7;
      f16x8 v = *(const f16x8*)(hw2T + ((size_t)tap * 64 + row) * 64 + ch * 8);
      *(f16x8*)(BsB + row * 128 + ((ch ^ (row & 7)) << 4)) = v;
    }
  }
  __syncthreads();
  f32x4 acc[4][4];
#pragma unroll
  for (int m = 0; m < 4; m++)
#pragma unroll
    for (int n = 0; n < 4; n++) acc[m][n] = (f32x4){0.f, 0.f, 0.f, 0.f};
#pragma unroll
  for (int ks = 0; ks < 2; ks++) {
    f16x8 af[4], bf[4];
#pragma unroll
    for (int m = 0; m < 4; m++) {
      int row = wid * 64 + m * 16 + (lane & 15);
      int c = ks * 4 + (lane >> 4);
      af[m] = *(const f16x8*)(AsB + row * 128 + ((c ^ (row & 7)) << 4));
    }
#pragma unroll
    for (int n = 0; n < 4; n++) {
      int row = n * 16 + (lane & 15);
      int c = ks * 4 + (lane >> 4);
      bf[n] = *(const f16x8*)(BsB + row * 128 + ((c ^ (row & 7)) << 4));
    }
#pragma unroll
    for (int m = 0; m < 4; m++)
#pragma unroll
      for (int n = 0; n < 4; n++)
        acc[m][n] = __builtin_amdgcn_mfma_f32_16x16x32_f16(af[m], bf[n], acc[m][n], 0, 0, 0);
  }
  const int kkm1 = (1 << l2kk) - 1;
#pragma unroll
  for (int n = 0; n < 4; n++) {
    int c = n * 16 + (lane & 15);
    float bj = b2T[tap * 64 + c];
#pragma unroll
    for (int m = 0; m < 4; m++) {
      int rbase = m0 + wid * 64 + m * 16 + (lane >> 4) * 4;
#pragma unroll
      for (int r = 0; r < 4; r++) {
        int row = rbase + r;
        if (row < M) {
          int o = row & 63, g = row >> 6;
          int i = g >> l2kk, jb = g & kkm1;
          wout[((size_t)tap * Cout + (i << 6) + o) * Cin + (jb << 6) + c] =
              (f16)(acc[m][n][r] + bj);
        }
      }
    }
  }
}

// ---------------- MFMA implicit-GEMM conv, 128x128 flagship (2-deep prefetch) ----------------
template <int FUSE>
__global__ __launch_bounds__(512) void k_conv_mfma(
    const f16* __restrict__ in, f16* __restrict__ outh, float* __restrict__ outf,
    const f16* __restrict__ wt, float* __restrict__ stats,
    int Cin, int Cout, int Hin, int l2W, int l2HW, int stride, int KS) {
  __shared__ f16 As[128 * 64];
  __shared__ f16 Bs[128 * 64];
  __shared__ float bns[256];

  const int t = threadIdx.x;
  const int lane = t & 63;
  const int wid = t >> 6;
  const int wm = wid >> 2, wn = wid & 3;

  const int gx = gridDim.x;
  const int nwg = gx * gridDim.y;
  const int flat = blockIdx.y * gx + blockIdx.x;
  const int qq = nwg >> 3, rr = nwg & 7;
  const int xcd = flat & 7, ii = flat >> 3;
  const int swz = (xcd < rr ? xcd * (qq + 1) : rr * (qq + 1) + (xcd - rr) * qq) + ii;
  const int m0 = (swz % gx) * 128, co0 = (swz / gx) * 128;

  if (FUSE && t < 256) bns[t] = 0.f;

  const int r0 = t >> 3;
  const int ch = t & 7;
  const f16* abase[2];
  unsigned vmask[2];
  const f16* bbase[2];
#pragma unroll
  for (int q = 0; q < 2; q++) {
    int pix = m0 + r0 + q * 64;
    int pn = pix >> l2HW;
    int prem = pix & ((1 << l2HW) - 1);
    int py = prem >> l2W;
    int px = prem & ((1 << l2W) - 1);
    long py0 = (long)py * stride - 1, px0 = (long)px * stride - 1;
    abase[q] = in + ((long)pn * Hin + py0) * Hin * Cin + px0 * Cin + ch * 8;
    unsigned m = 0;
#pragma unroll
    for (int tt = 0; tt < 9; tt++) {
      int iy = py * stride + tt / 3 - 1;
      int ix = px * stride + tt % 3 - 1;
      if ((unsigned)iy < (unsigned)Hin && (unsigned)ix < (unsigned)Hin) m |= 1u << tt;
    }
    vmask[q] = m;
    bbase[q] = wt + (size_t)(co0 + r0 + q * 64) * Cin + ch * 8;
  }
  const size_t bTap = (size_t)Cout * Cin;

  char* AsB = (char*)As;
  char* BsB = (char*)Bs;
  const int aw0 = r0 * 128 + ((ch ^ (r0 & 7)) << 4);
  const int aw1 = (r0 + 64) * 128 + ((ch ^ (r0 & 7)) << 4);

  int aro[4][2], bro[2][2];
#pragma unroll
  for (int m = 0; m < 4; m++) {
    int row = wm * 64 + m * 16 + (lane & 15);
#pragma unroll
    for (int ks = 0; ks < 2; ks++) {
      int c = ks * 4 + (lane >> 4);
      aro[m][ks] = row * 128 + ((c ^ (row & 7)) << 4);
    }
  }
#pragma unroll
  for (int n = 0; n < 2; n++) {
    int row = wn * 32 + n * 16 + (lane & 15);
#pragma unroll
    for (int ks = 0; ks < 2; ks++) {
      int c = ks * 4 + (lane >> 4);
      bro[n][ks] = row * 128 + ((c ^ (row & 7)) << 4);
    }
  }

  f32x4 acc[4][2];
#pragma unroll
  for (int m = 0; m < 4; m++)
#pragma unroll
    for (int n = 0; n < 2; n++) acc[m][n] = (f32x4){0.f, 0.f, 0.f, 0.f};

  const int ck = Cin >> 6;
  const int S = 9 * ck;
  int sBeg = 0, sEnd = S;
  if (!FUSE) {
    sBeg = (int)(((long)blockIdx.z * S) / KS);
    sEnd = (int)(((long)(blockIdx.z + 1) * S) / KS);
  }
  int tap = sBeg % 9;
  int kin = (sBeg / 9) << 6;

  f16x8 zz = {};
  f16x8 avc[2], bvc[2], avn[2], bvn[2];
  {
    const int aoff = ((tap / 3) * Hin + (tap % 3)) * Cin + kin;
    const size_t boff = (size_t)tap * bTap + kin;
#pragma unroll
    for (int q = 0; q < 2; q++) {
      avc[q] = ((vmask[q] >> tap) & 1) ? *(const f16x8*)(abase[q] + aoff) : zz;
      bvc[q] = *(const f16x8*)(bbase[q] + boff);
    }
  }
  if (sBeg + 1 < sEnd) {
    tap++; if (tap == 9) { tap = 0; kin += 64; }
    const int aoff = ((tap / 3) * Hin + (tap % 3)) * Cin + kin;
    const size_t boff = (size_t)tap * bTap + kin;
#pragma unroll
    for (int q = 0; q < 2; q++) {
      avn[q] = ((vmask[q] >> tap) & 1) ? *(const f16x8*)(abase[q] + aoff) : zz;
      bvn[q] = *(const f16x8*)(bbase[q] + boff);
    }
  }

  for (int s = sBeg; s < sEnd; s++) {
    __syncthreads();
    *(f16x8*)(AsB + aw0) = avc[0];
    *(f16x8*)(AsB + aw1) = avc[1];
    *(f16x8*)(BsB + aw0) = bvc[0];
    *(f16x8*)(BsB + aw1) = bvc[1];
    __syncthreads();
#pragma unroll
    for (int q = 0; q < 2; q++) { avc[q] = avn[q]; bvc[q] = bvn[q]; }
    if (s + 2 < sEnd) {  // issue loads 2 steps ahead
      tap++; if (tap == 9) { tap = 0; kin += 64; }
      const int aoff = ((tap / 3) * Hin + (tap % 3)) * Cin + kin;
      const size_t boff = (size_t)tap * bTap + kin;
#pragma unroll
      for (int q = 0; q < 2; q++) {
        avn[q] = ((vmask[q] >> tap) & 1) ? *(const f16x8*)(abase[q] + aoff) : zz;
        bvn[q] = *(const f16x8*)(bbase[q] + boff);
      }
    }
#pragma unroll
    for (int ks = 0; ks < 2; ks++) {
      f16x8 af[4], bf[2];
#pragma unroll
      for (int m = 0; m < 4; m++) af[m] = *(const f16x8*)(AsB + aro[m][ks]);
#pragma unroll
      for (int n = 0; n < 2; n++) bf[n] = *(const f16x8*)(BsB + bro[n][ks]);
#pragma unroll
      for (int m = 0; m < 4; m++)
#pragma unroll
        for (int n = 0; n < 2; n++)
          acc[m][n] = __builtin_amdgcn_mfma_f32_16x16x32_f16(af[m], bf[n], acc[m][n], 0, 0, 0);
    }
  }

  const int colL = lane & 15;
  const int rowL = (lane >> 4) * 4;
#pragma unroll
  for (int m = 0; m < 4; m++) {
    int prow = m0 + wm * 64 + m * 16 + rowL;
#pragma unroll
    for (int n = 0; n < 2; n++) {
      int col = co0 + wn * 32 + n * 16 + colL;
      if (col < Cout) {
        if (FUSE) {
#pragma unroll
          for (int r = 0; r < 4; r++)
            outh[(size_t)(prow + r) * Cout + col] = (f16)acc[m][n][r];
        } else {
#pragma unroll
          for (int r = 0; r < 4; r++)
            atomicAdd(&outf[(size_t)(prow + r) * Cout + col], acc[m][n][r]);
        }
      }
    }
  }
  if (FUSE) {
#pragma unroll
    for (int n = 0; n < 2; n++) {
      float s1 = 0.f, s2 = 0.f;
#pragma unroll
      for (int m = 0; m < 4; m++)
#pragma unroll
        for (int r = 0; r < 4; r++) { float v = acc[m][n][r]; s1 += v; s2 += v * v; }
      s1 += __shfl_xor(s1, 16); s2 += __shfl_xor(s2, 16);
      s1 += __shfl_xor(s1, 32); s2 += __shfl_xor(s2, 32);
      if (lane < 16) {
        int c = wn * 32 + n * 16 + colL;
        atomicAdd(&bns[c], s1);
        atomicAdd(&bns[128 + c], s2);
      }
    }
    __syncthreads();
    if (t < 128 && co0 + t < Cout) {
      atomicAdd(&stats[co0 + t], bns[t]);
      atomicAdd(&stats[Cout + co0 + t], bns[128 + t]);
    }
  }
}

// ---------------- generalized small-tile conv: MT x NT, NTHR threads (2-deep prefetch) ----------------
template <int FUSE, int MT, int NT, int NTHR>
__global__ __launch_bounds__(NTHR) void k_conv_s(
    const f16* __restrict__ in, f16* __restrict__ outh, float* __restrict__ outf,
    const f16* __restrict__ wt, float* __restrict__ stats,
    int Cin, int Cout, int Hin, int l2W, int l2HW, int stride, int KS) {
  constexpr int WN = NT / 32;
  constexpr int RP = NTHR / 8;
  constexpr int NA = MT / RP;
  constexpr int NB = NT / RP;
  __shared__ f16 As[MT * 64];
  __shared__ f16 Bs[NT * 64];
  __shared__ float bns[2 * NT];

  const int t = threadIdx.x;
  const int lane = t & 63;
  const int wid = t >> 6;
  const int wm = wid / WN, wn = wid % WN;

  const int gx = gridDim.x;
  const int nwg = gx * gridDim.y;
  const int flat = blockIdx.y * gx + blockIdx.x;
  const int qq = nwg >> 3, rr = nwg & 7;
  const int xcd = flat & 7, ii = flat >> 3;
  const int swz = (xcd < rr ? xcd * (qq + 1) : rr * (qq + 1) + (xcd - rr) * qq) + ii;
  const int m0 = (swz % gx) * MT, co0 = (swz / gx) * NT;

  if (FUSE && t < 2 * NT) bns[t] = 0.f;

  const int r0 = t >> 3;
  const int ch = t & 7;
  const f16* abase[NA];
  unsigned vmask[NA];
  const f16* bbase[NB];
#pragma unroll
  for (int q = 0; q < NA; q++) {
    int pix = m0 + r0 + q * RP;
    int pn = pix >> l2HW;
    int prem = pix & ((1 << l2HW) - 1);
    int py = prem >> l2W;
    int px = prem & ((1 << l2W) - 1);
    long py0 = (long)py * stride - 1, px0 = (long)px * stride - 1;
    abase[q] = in + ((long)pn * Hin + py0) * Hin * Cin + px0 * Cin + ch * 8;
    unsigned m = 0;
#pragma unroll
    for (int tt = 0; tt < 9; tt++) {
      int iy = py * stride + tt / 3 - 1;
      int ix = px * stride + tt % 3 - 1;
      if ((unsigned)iy < (unsigned)Hin && (unsigned)ix < (unsigned)Hin) m |= 1u << tt;
    }
    vmask[q] = m;
  }
#pragma unroll
  for (int q = 0; q < NB; q++)
    bbase[q] = wt + (size_t)(co0 + r0 + q * RP) * Cin + ch * 8;
  const size_t bTap = (size_t)Cout * Cin;

  char* AsB = (char*)As;
  char* BsB = (char*)Bs;
  int awo[NA], bwo[NB];
#pragma unroll
  for (int q = 0; q < NA; q++) {
    int row = r0 + q * RP;
    awo[q] = row * 128 + ((ch ^ (row & 7)) << 4);
  }
#pragma unroll
  for (int q = 0; q < NB; q++) {
    int row = r0 + q * RP;
    bwo[q] = row * 128 + ((ch ^ (row & 7)) << 4);
  }

  int aro[2][2], bro[2][2];
#pragma unroll
  for (int m = 0; m < 2; m++) {
    int row = wm * 32 + m * 16 + (lane & 15);
#pragma unroll
    for (int ks = 0; ks < 2; ks++) {
      int c = ks * 4 + (lane >> 4);
      aro[m][ks] = row * 128 + ((c ^ (row & 7)) << 4);
    }
  }
#pragma unroll
  for (int n = 0; n < 2; n++) {
    int row = wn * 32 + n * 16 + (lane & 15);
#pragma unroll
    for (int ks = 0; ks < 2; ks++) {
      int c = ks * 4 + (lane >> 4);
      bro[n][ks] = row * 128 + ((c ^ (row & 7)) << 4);
    }
  }

  f32x4 acc[2][2];
#pragma unroll
  for (int m = 0; m < 2; m++)
#pragma unroll
    for (int n = 0; n < 2; n++) acc[m][n] = (f32x4){0.f, 0.f, 0.f, 0.f};

  const int ck = Cin >> 6;
  const int S = 9 * ck;
  int sBeg = 0, sEnd = S;
  if (!FUSE) {
    sBeg = (int)(((long)blockIdx.z * S) / KS);
    sEnd = (int)(((long)(blockIdx.z + 1) * S) / KS);
  }
  int tap = sBeg % 9;
  int kin = (sBeg / 9) << 6;

  f16x8 zz = {};
  f16x8 avc[NA], bvc[NB], avn[NA], bvn[NB];
  {
    const int aoff = ((tap / 3) * Hin + (tap % 3)) * Cin + kin;
    const size_t boff = (size_t)tap * bTap + kin;
#pragma unroll
    for (int q = 0; q < NA; q++)
      avc[q] = ((vmask[q] >> tap) & 1) ? *(const f16x8*)(abase[q] + aoff) : zz;
#pragma unroll
    for (int q = 0; q < NB; q++) bvc[q] = *(const f16x8*)(bbase[q] + boff);
  }
  if (sBeg + 1 < sEnd) {
    tap++; if (tap == 9) { tap = 0; kin += 64; }
    const int aoff = ((tap / 3) * Hin + (tap % 3)) * Cin + kin;
    const size_t boff = (size_t)tap * bTap + kin;
#pragma unroll
    for (int q = 0; q < NA; q++)
      avn[q] = ((vmask[q] >> tap) & 1) ? *(const f16x8*)(abase[q] + aoff) : zz;
#pragma unroll
    for (int q = 0; q < NB; q++) bvn[q] = *(const f16x8*)(bbase[q] + boff);
  }

  for (int s = sBeg; s < sEnd; s++) {
    __syncthreads();
#pragma unroll
    for (int q = 0; q < NA; q++) *(f16x8*)(AsB + awo[q]) = avc[q];
#pragma unroll
    for (int q = 0; q < NB; q++) *(f16x8*)(BsB + bwo[q]) = bvc[q];
    __syncthreads();
#pragma unroll
    for (int q = 0; q < NA; q++) avc[q] = avn[q];
#pragma unroll
    for (int q = 0; q < NB; q++) bvc[q] = bvn[q];
    if (s + 2 < sEnd) {  // issue loads 2 steps ahead
      tap++; if (tap == 9) { tap = 0; kin += 64; }
      const int aoff = ((tap / 3) * Hin + (tap % 3)) * Cin + kin;
      const size_t boff = (size_t)tap * bTap + kin;
#pragma unroll
      for (int q = 0; q < NA; q++)
        avn[q] = ((vmask[q] >> tap) & 1) ? *(const f16x8*)(abase[q] + aoff) : zz;
#pragma unroll
      for (int q = 0; q < NB; q++) bvn[q] = *(const f16x8*)(bbase[q] + boff);
    }
#pragma unroll
    for (int ks = 0; ks < 2; ks++) {
      f16x8 af[2], bf[2];
#pragma unroll
      for (int m = 0; m < 2; m++) af[m] = *(const f16x8*)(AsB + aro[m][ks]);
#pragma unroll
      for (int n = 0; n < 2; n++) bf[n] = *(const f16x8*)(BsB + bro[n][ks]);
#pragma unroll
      for (int m = 0; m < 2; m++)
#pragma unroll
        for (int n = 0; n < 2; n++)
          acc[m][n] = __builtin_amdgcn_mfma_f32_16x16x32_f16(af[m], bf[n], acc[m][n], 0, 0, 0);
    }
  }

  const int colL = lane & 15;
  const int rowL = (lane >> 4) * 4;
#pragma unroll
  for (int m = 0; m < 2; m++) {
    int prow = m0 + wm * 32 + m * 16 + rowL;
#pragma unroll
    for (int n = 0; n < 2; n++) {
      int col = co0 + wn * 32 + n * 16 + colL;
      if (col < Cout) {
        if (FUSE) {
#pragma unroll
          for (int r = 0; r < 4; r++)
            outh[(size_t)(prow + r) * Cout + col] = (f16)acc[m][n][r];
        } else {
#pragma unroll
          for (int r = 0; r < 4; r++)
            atomicAdd(&outf[(size_t)(prow + r) * Cout + col], acc[m][n][r]);
        }
      }
    }
  }
  if (FUSE) {
#pragma unroll
    for (int n = 0; n < 2; n++) {
      float s1 = 0.f, s2 = 0.f;
#pragma unroll
      for (int m = 0; m < 2; m++)
#pragma unroll
        for (int r = 0; r < 4; r++) { float v = acc[m][n][r]; s1 += v; s2 += v * v; }
      s1 += __shfl_xor(s1, 16); s2 += __shfl_xor(s2, 16);
      s1 += __shfl_xor(s1, 32); s2 += __shfl_xor(s2, 32);
      if (lane < 16) {
        int c = wn * 32 + n * 16 + colL;
        atomicAdd(&bns[c], s1);
        atomicAdd(&bns[NT + c], s2);
      }
    }
    __syncthreads();
    if (t < NT && co0 + t < Cout) {
      atomicAdd(&stats[co0 + t], bns[t]);
      atomicAdd(&stats[Cout + co0 + t], bns[NT + t]);
    }
  }
}

// ---------------- batchnorm helpers ----------------
template <typename T>
__global__ void k_bnstats_nhwc(const T* __restrict__ t, float* __restrict__ acc,
                               int C, int npix, int pps) {
  int c = blockIdx.y * 64 + (threadIdx.x & 63);
  int pr = threadIdx.x >> 6;
  int p0 = blockIdx.x * pps;
  int pend = min(p0 + pps, npix);
  float s = 0.f, s2 = 0.f;
  for (int p = p0 + pr; p < pend; p += 4) {
    float v = (float)t[(size_t)p * C + c];
    s += v; s2 += v * v;
  }
  __shared__ float sh1[256], sh2[256];
  sh1[threadIdx.x] = s; sh2[threadIdx.x] = s2;
  __syncthreads();
  if (threadIdx.x < 64) {
    s = sh1[threadIdx.x] + sh1[threadIdx.x + 64] + sh1[threadIdx.x + 128] + sh1[threadIdx.x + 192];
    s2 = sh2[threadIdx.x] + sh2[threadIdx.x + 64] + sh2[threadIdx.x + 128] + sh2[threadIdx.x + 192];
    atomicAdd(&acc[c], s);
    atomicAdd(&acc[C + c], s2);
  }
}

// normalize + optional residual-add + optional relu; C power of two
template <typename T>
__global__ void k_bnapply(const T* __restrict__ src, const f16* __restrict__ res,
                          f16* __restrict__ dst, const float* __restrict__ st,
                          int C, float invn, int total8, int relu) {
  int idx = blockIdx.x * TPB + threadIdx.x;
  if (idx >= total8) return;
  size_t base = (size_t)idx * 8;
  int c0 = (int)(base & (size_t)(C - 1));
  float v[8];
  if constexpr (sizeof(T) == 2) {
    f16x8 x = *(const f16x8*)(src + base);
#pragma unroll
    for (int q = 0; q < 8; q++) v[q] = (float)x[q];
  } else {
    f32x4 x0 = *(const f32x4*)(src + base);
    f32x4 x1 = *(const f32x4*)(src + base + 4);
#pragma unroll
    for (int q = 0; q < 4; q++) { v[q] = x0[q]; v[q + 4] = x1[q]; }
  }
  f16x8 rv;
  if (res) rv = *(const f16x8*)(res + base);
  f16x8 o;
#pragma unroll
  for (int q = 0; q < 8; q++) {
    int c = c0 + q;
    float mean = st[c] * invn;
    float var = st[C + c] * invn - mean * mean;
    float f = (v[q] - mean) * rsqrtf(var + 1e-5f);
    if (res) f += (float)rv[q];
    if (relu) f = fmaxf(f, 0.f);
    o[q] = (f16)f;
  }
  *(f16x8*)(dst + base) = o;
}

// ---------------- input BN (NCHW fp32; raw sums via 192 blocks + atomics) ----------------
__global__ void k_bnstats_x(const float* __restrict__ t, float* __restrict__ mvx) {
  int n = blockIdx.x / 3, c = blockIdx.x - 3 * n;
  const float* p = t + ((size_t)n * 3 + c) * 1024;
  float s = 0.f, s2 = 0.f;
  for (int i = threadIdx.x; i < 1024; i += TPB) { float v = p[i]; s += v; s2 += v * v; }
#pragma unroll
  for (int off = 32; off > 0; off >>= 1) { s += __shfl_down(s, off); s2 += __shfl_down(s2, off); }
  __shared__ float sh[8];
  int wid = threadIdx.x >> 6;
  if ((threadIdx.x & 63) == 0) { sh[wid * 2] = s; sh[wid * 2 + 1] = s2; }
  __syncthreads();
  if (threadIdx.x == 0) {
    for (int w = 1; w < TPB / 64; w++) { s += sh[w * 2]; s2 += sh[w * 2 + 1]; }
    atomicAdd(&mvx[c], s);
    atomicAdd(&mvx[4 + c], s2);
  }
}

// finalize from raw sums inside apply (n=65536 elems per channel)
__global__ void k_apply_x(const float* __restrict__ src, f16* __restrict__ dst,
                          const float* __restrict__ mvx, int total) {
  int idx = blockIdx.x * TPB + threadIdx.x;
  if (idx >= total) return;
  int r = idx & 1023;
  int cch = (idx >> 10) % 3;
  int n = idx / 3072;
  const float invn = 1.f / 65536.f;
  float mean = mvx[cch] * invn;
  float var = mvx[4 + cch] * invn - mean * mean;
  float v = (src[idx] - mean) * rsqrtf(var + 1e-5f);
  dst[((size_t)(n * 1024 + r)) * 64 + cch] = (f16)v;
}

// ---------------- pool + final linear (NHWC) ----------------
__global__ void k_poolfc(const f16* __restrict__ in, const float* __restrict__ fw,
                         const float* __restrict__ fb, float* __restrict__ out) {
  __shared__ float pooled[2048];
  __shared__ float red[4];
  int n = blockIdx.x;
  for (int c = threadIdx.x; c < 2048; c += TPB) {
    float s = 0.f;
#pragma unroll
    for (int p = 0; p < 16; p++) s += (float)in[((size_t)n * 16 + p) * 2048 + c];
    pooled[c] = s * (1.f / 16.f);
  }
  __syncthreads();
  for (int kk = 0; kk < 10; kk++) {
    float s = 0.f;
    for (int c = threadIdx.x; c < 2048; c += TPB) s += pooled[c] * fw[kk * 2048 + c];
#pragma unroll
    for (int off = 32; off > 0; off >>= 1) s += __shfl_down(s, off);
    if ((threadIdx.x & 63) == 0) red[threadIdx.x >> 6] = s;
    __syncthreads();
    if (threadIdx.x == 0) out[n * 10 + kk] = red[0] + red[1] + red[2] + red[3] + fb[kk];
    __syncthreads();
  }
}

extern "C" void kernel_launch(void* const* d_in, const int* in_sizes, int n_in,
                              void* d_out, int out_size, void* d_ws, size_t ws_size,
                              hipStream_t stream) {
  static const int ZS_H[52] = {1,1,4,4,1,1,4,1,1,4,2,2,8,8,2,2,8,2,2,8,2,2,8,4,4,16,16,
                               4,4,16,4,4,16,4,4,16,4,4,16,4,4,16,8,8,32,32,8,8,32,8,8,32};
  static const int ZS_K[52] = {1,1,1,1,4,1,1,4,1,1,4,2,2,4,8,2,2,8,2,2,8,2,2,8,4,4,8,
                               16,4,4,16,4,4,16,4,4,16,4,4,16,4,4,16,8,8,16,32,8,8,32,8,8};
  int offz[52];
  { int a = 0; for (int t = 0; t < 52; t++) { offz[t] = a; a += ZS_H[t] * ZS_K[t]; } }

  const float* x     = (const float*)d_in[0];
  const float* c1w   = (const float*)d_in[1];
  const float* z_all = (const float*)d_in[2];
  const float* hw1   = (const float*)d_in[3];
  const float* hb1   = (const float*)d_in[4];
  const float* hw2   = (const float*)d_in[5];
  const float* hb2   = (const float*)d_in[6];
  const float* fw    = (const float*)d_in[7];
  const float* fb    = (const float*)d_in[8];
  float* out = (float*)d_out;

  // ---- workspace layout (~191 MiB) ----
  char* ws = (char*)d_ws;
  size_t pos = 0;
  auto take = [&](size_t b) -> char* { char* p = ws + pos; pos += (b + 255) & ~(size_t)255; return p; };
  f16*   wbuf    = (f16*)take((size_t)512 * 64 * 576 * 2);   // 37.75 MiB
  f16*   hbuf    = (f16*)take((size_t)3268 * 4096 * 2);      // 26.8 MiB
  f16*   A       = (f16*)take((size_t)16777216 * 2);         // 32 MiB
  f16*   B       = (f16*)take((size_t)16777216 * 2);
  f16*   C_      = (f16*)take((size_t)16777216 * 2);
  float* scratch = (float*)take((size_t)16 << 20);           // 16 MiB fp32 split-K acc
  f16*   xn64    = (f16*)take((size_t)64 * 1024 * 64 * 2);   // 8 MiB channel-padded input
  float* mv      = (float*)take(2 * 2048 * 4);
  float* mv2     = (float*)take(2 * 2048 * 4);
  float* mvx     = (float*)take(8 * 4);
  f16*   hw1T    = (f16*)take((size_t)4096 * 64 * 2);
  f16*   hw2T    = (f16*)take((size_t)576 * 64 * 2);
  float* b2T     = (float*)take(576 * 4);
  f16*   stemW   = (f16*)take((size_t)10 * 64 * 64 * 2);
  if (ws_size < pos) return;

  // ---- one-time prep ----
  hipMemsetAsync(xn64, 0, (size_t)64 * 1024 * 64 * 2, stream);
  k_prep_hw1<<<(4096 * 64 + TPB - 1) / TPB, TPB, 0, stream>>>(hw1, hw1T);
  k_prep_hw2<<<(576 * 64 + TPB - 1) / TPB, TPB, 0, stream>>>(hw2, hb2, hw2T, b2T, mv, mvx);
  k_prep_stemw<<<(10 * 64 * 64 + TPB - 1) / TPB, TPB, 0, stream>>>(c1w, stemW);
  k_gen_h_mfma<<<dim3(13, 64), 256, 0, stream>>>(z_all, hw1T, hb1, hbuf, 3268);

  auto genw = [&](int jj, float* st, int Cout) {
    int nr = ZS_H[jj] * ZS_K[jj];
    int CoutW = ZS_H[jj] * 64, CinW = ZS_K[jj] * 64;
    int M = nr * 64;
    int l2kk = __builtin_ctz(ZS_K[jj]);
    k_gen_w<<<dim3((unsigned)((M + 255) / 256), 9), 256, 0, stream>>>(
        hbuf, hw2T, b2T, wbuf, offz[jj] * 64, M, l2kk, CinW, CoutW, st, 2 * Cout);
  };

  // returns true if split-K path (result in fp32 scratch), false if fused (f16 in dst)
  auto conv = [&](const f16* src, f16* dst, int jj, int Cin, int Cout,
                  int Hin, int Hout, int s, float* st) -> bool {
    genw(jj, st, Cout);
    int M = 64 * Hout * Hout;
    int S = 9 * (Cin >> 6);
    int l2W = (Hout == 32) ? 5 : (Hout == 16) ? 4 : (Hout == 8) ? 3 : 2;
    if (Cout == 64) {  // no-waste N=64 path (stage-1 conv1/conv2 + stem)
      k_conv_s<1, 128, 64, 512><<<dim3(M / 128, 1, 1), 512, 0, stream>>>(
          src, dst, nullptr, wbuf, st, Cin, Cout, Hin, l2W, 2 * l2W, s, 1);
      return false;
    }
    int nat128 = (M / 128) * ((Cout + 127) / 128);
    if (nat128 >= 480) {  // big convs: flagship with >=2 blocks/CU
      k_conv_mfma<1><<<dim3(M / 128, (Cout + 127) / 128, 1), 512, 0, stream>>>(
          src, dst, nullptr, wbuf, st, Cin, Cout, Hin, l2W, 2 * l2W, s, 1);
      return false;
    }
    int nat64 = (M / 64) * (Cout / 64);
    if (nat64 >= 480) {  // mid convs: 64x64 4-wave blocks, >=2 blocks/CU
      k_conv_s<1, 64, 64, 256><<<dim3(M / 64, Cout / 64, 1), 256, 0, stream>>>(
          src, dst, nullptr, wbuf, st, Cin, Cout, Hin, l2W, 2 * l2W, s, 1);
      return false;
    }
    int ks = (480 + nat64 - 1) / nat64;
    if (ks > S) ks = S;
    if (ks > 16) ks = 16;
    hipMemsetAsync(scratch, 0, (size_t)M * Cout * 4, stream);
    k_conv_s<0, 64, 64, 256><<<dim3(M / 64, Cout / 64, ks), 256, 0, stream>>>(
        src, nullptr, scratch, wbuf, nullptr, Cin, Cout, Hin, l2W, 2 * l2W, s, ks);
    dim3 g((unsigned)((M + 63) / 64), (unsigned)(Cout / 64));
    k_bnstats_nhwc<float><<<g, TPB, 0, stream>>>(scratch, st, Cout, M, 64);
    return true;
  };

  auto applyF = [&](bool split, const f16* rawh, const f16* res, f16* dst, float* st,
                    int C, int npix, int relu) {
    int tot8 = npix * C / 8;
    int g = (tot8 + TPB - 1) / TPB;
    if (split)
      k_bnapply<float><<<g, TPB, 0, stream>>>(scratch, res, dst, st, C, 1.f / npix, tot8, relu);
    else
      k_bnapply<f16><<<g, TPB, 0, stream>>>(rawh, res, dst, st, C, 1.f / npix, tot8, relu);
  };

  // ---- data bn: NCHW fp32 -> channel-padded NHWC C=64 fp16 (mvx zeroed in prep) ----
  k_bnstats_x<<<192, TPB, 0, stream>>>(x, mvx);
  { int tot = 64 * 3 * 1024;
    k_apply_x<<<(tot + TPB - 1) / TPB, TPB, 0, stream>>>(x, xn64, mvx, tot); }

  // ---- stem as MFMA conv (Cin=64 padded, Cout=64) + fused stats (mv zeroed in prep) ----
  k_conv_s<1, 128, 64, 512><<<dim3(512, 1, 1), 512, 0, stream>>>(
      xn64, A, nullptr, stemW, mv, 64, 64, 32, 5, 10, 1, 1);
  applyF(false, A, nullptr, A, mv, 64, 64 * 1024, 1);

  // ---- 16 residual blocks ----
  f16* P[3] = {A, B, C_};
  int cur = 0, H = 32, j = 0, cin = 64;
  for (int i = 0; i < 16; i++) {
    bool hasSc = (i == 0 || i == 3 || i == 7 || i == 13);
    int s = (hasSc && i != 0) ? 2 : 1;
    int cmid = ZS_H[j] * 64;
    int cout = ZS_H[j + 2] * 64;
    int Hin = H, Hout = H / s;
    int f1 = (cur + 1) % 3, f2 = (cur + 2) % 3;

    bool c1 = conv(P[cur], P[f1], j, cin, cmid, Hin, Hin, 1, mv);
    applyF(c1, P[f1], nullptr, P[f1], mv, cmid, 64 * Hin * Hin, 1);

    bool c2 = conv(P[f1], P[f2], j + 1, cmid, cmid, Hin, Hout, s, mv);
    applyF(c2, P[f2], nullptr, P[f2], mv, cmid, 64 * Hout * Hout, 1);

    if (hasSc) {
      bool cs = conv(P[cur], P[f1], j + 3, cin, cout, Hin, Hout, s, mv2);
      applyF(cs, P[f1], nullptr, P[f1], mv2, cout, 64 * Hout * Hout, 0);
      bool c3 = conv(P[f2], P[cur], j + 2, cmid, cout, Hout, Hout, 1, mv);
      applyF(c3, P[cur], P[f1], P[cur], mv, cout, 64 * Hout * Hout, 1);
      j += 4;
    } else {
      bool c3 = conv(P[f2], P[f1], j + 2, cmid, cout, Hout, Hout, 1, mv);
      applyF(c3, P[f1], P[cur], P[f2], mv, cout, 64 * Hout * Hout, 1);
      cur = f2;
      j += 3;
    }
    cin = cout; H = Hout;
  }

  // ---- pool + fc ----
  k_poolfc<<<64, TPB, 0, stream>>>(P[cur], fw, fb, out);
}

// Round 17
// 2958.762 us; speedup vs baseline: 1.0851x; 1.0851x over previous
//
#include <hip/hip_runtime.h>
#include <hip/hip_fp16.h>

#define TPB 256

typedef _Float16 f16;
typedef __attribute__((ext_vector_type(8))) _Float16 f16x8;
typedef __attribute__((ext_vector_type(4))) float f32x4;

// ---------------- one-time transposes ----------------
__global__ void k_prep_hw1(const float* __restrict__ hw1, f16* __restrict__ hw1T) {
  int idx = blockIdx.x * TPB + threadIdx.x;
  if (idx >= 4096 * 64) return;
  int z = idx & 63, n = idx >> 6;
  hw1T[idx] = (f16)hw1[z * 4096 + n];
}

__global__ void k_prep_hw2(const float* __restrict__ hw2, const float* __restrict__ hb2,
                           f16* __restrict__ hw2T, float* __restrict__ b2T,
                           float* __restrict__ stz, float* __restrict__ mvxz) {
  int idx = blockIdx.x * TPB + threadIdx.x;
  if (idx < 128) stz[idx] = 0.f;
  if (idx < 8) mvxz[idx] = 0.f;
  if (idx >= 576 * 64) return;
  int z = idx & 63, j = idx >> 6;
  int tap = j >> 6, c = j & 63;
  hw2T[(size_t)j * 64 + z] = (f16)hw2[z * 576 + c * 9 + tap];
  if (z == 0) b2T[j] = hb2[c * 9 + tap];
}

// stem weights: conv B^T layout [tap][co=64][ci=64], 10th tap zero pad
__global__ void k_prep_stemw(const float* __restrict__ w, f16* __restrict__ sw) {
  int idx = blockIdx.x * TPB + threadIdx.x;
  if (idx >= 10 * 64 * 64) return;
  int ci = idx & 63, co = (idx >> 6) & 63, tap = idx >> 12;
  float v = 0.f;
  if (tap < 9 && ci < 3) v = w[co * 27 + ci * 9 + tap];
  sw[idx] = (f16)v;
}

// ---------------- gen_h: h[3268 x 4096] = z @ hw1T^T + hb1 (MFMA) ----------------
__global__ __launch_bounds__(256) void k_gen_h_mfma(
    const float* __restrict__ z, const f16* __restrict__ hw1T, const float* __restrict__ hb1,
    f16* __restrict__ h, int M) {
  __shared__ f16 As[256 * 64];
  __shared__ f16 Bs[64 * 64];
  const int t = threadIdx.x, lane = t & 63, wid = t >> 6;
  const int m0 = blockIdx.x * 256;
  const int n0 = blockIdx.y * 64;
  char* AsB = (char*)As;
  char* BsB = (char*)Bs;
  {
    int row = t;
    bool ok = (m0 + row) < M;
    const float* src = z + (size_t)(m0 + row) * 64;
#pragma unroll
    for (int ch = 0; ch < 8; ch++) {
      f16x8 v = {};
      if (ok) {
        f32x4 a = *(const f32x4*)(src + ch * 8);
        f32x4 b = *(const f32x4*)(src + ch * 8 + 4);
#pragma unroll
        for (int q = 0; q < 4; q++) { v[q] = (f16)a[q]; v[q + 4] = (f16)b[q]; }
      }
      *(f16x8*)(AsB + row * 128 + ((ch ^ (row & 7)) << 4)) = v;
    }
  }
  {
#pragma unroll
    for (int q = 0; q < 2; q++) {
      int id = t + q * 256;
      int row = id >> 3, ch = id & 7;
      f16x8 v = *(const f16x8*)(hw1T + ((size_t)(n0 + row)) * 64 + ch * 8);
      *(f16x8*)(BsB + row * 128 + ((ch ^ (row & 7)) << 4)) = v;
    }
  }
  __syncthreads();
  f32x4 acc[4][4];
#pragma unroll
  for (int m = 0; m < 4; m++)
#pragma unroll
    for (int n = 0; n < 4; n++) acc[m][n] = (f32x4){0.f, 0.f, 0.f, 0.f};
#pragma unroll
  for (int ks = 0; ks < 2; ks++) {
    f16x8 af[4], bf[4];
#pragma unroll
    for (int m = 0; m < 4; m++) {
      int row = wid * 64 + m * 16 + (lane & 15);
      int c = ks * 4 + (lane >> 4);
      af[m] = *(const f16x8*)(AsB + row * 128 + ((c ^ (row & 7)) << 4));
    }
#pragma unroll
    for (int n = 0; n < 4; n++) {
      int row = n * 16 + (lane & 15);
      int c = ks * 4 + (lane >> 4);
      bf[n] = *(const f16x8*)(BsB + row * 128 + ((c ^ (row & 7)) << 4));
    }
#pragma unroll
    for (int m = 0; m < 4; m++)
#pragma unroll
      for (int n = 0; n < 4; n++)
        acc[m][n] = __builtin_amdgcn_mfma_f32_16x16x32_f16(af[m], bf[n], acc[m][n], 0, 0, 0);
  }
#pragma unroll
  for (int n = 0; n < 4; n++) {
    int c = n * 16 + (lane & 15);
    float bj = hb1[n0 + c];
#pragma unroll
    for (int m = 0; m < 4; m++) {
      int rbase = m0 + wid * 64 + m * 16 + (lane >> 4) * 4;
#pragma unroll
      for (int r = 0; r < 4; r++) {
        int row = rbase + r;
        if (row < M) h[(size_t)row * 4096 + n0 + c] = (f16)(acc[m][n][r] + bj);
      }
    }
  }
}

// ---------------- gen_w: scatter into w[tap][co][ci]; block0 zeroes upcoming stats ----------------
__global__ __launch_bounds__(256) void k_gen_w(
    const f16* __restrict__ h, const f16* __restrict__ hw2T, const float* __restrict__ b2T,
    f16* __restrict__ wout, int hoff, int M, int l2kk, int Cin, int Cout,
    float* __restrict__ st, int stClr) {
  __shared__ f16 As[256 * 64];
  __shared__ f16 Bs[64 * 64];
  const int t = threadIdx.x, lane = t & 63, wid = t >> 6;
  const int m0 = blockIdx.x * 256;
  const int tap = blockIdx.y;
  char* AsB = (char*)As;
  char* BsB = (char*)Bs;
  if (blockIdx.x == 0 && blockIdx.y == 0)
    for (int i = t; i < stClr; i += 256) st[i] = 0.f;
  {
    int row = t;
    const f16* src = h + (size_t)(hoff + m0 + row) * 64;
    bool ok = (m0 + row) < M;
#pragma unroll
    for (int ch = 0; ch < 8; ch++) {
      f16x8 v = {};
      if (ok) v = *(const f16x8*)(src + ch * 8);
      *(f16x8*)(AsB + row * 128 + ((ch ^ (row & 7)) << 4)) = v;
    }
  }
  {
#pragma unroll
    for (int q = 0; q < 2; q++) {
      int id = t + q * 256;
      int row = id >> 3, ch = id & 7;
      f16x8 v = *(const f16x8*)(hw2T + ((size_t)tap * 64 + row) * 64 + ch * 8);
      *(f16x8*)(BsB + row * 128 + ((ch ^ (row & 7)) << 4)) = v;
    }
  }
  __syncthreads();
  f32x4 acc[4][4];
#pragma unroll
  for (int m = 0; m < 4; m++)
#pragma unroll
    for (int n = 0; n < 4; n++) acc[m][n] = (f32x4){0.f, 0.f, 0.f, 0.f};
#pragma unroll
  for (int ks = 0; ks < 2; ks++) {
    f16x8 af[4], bf[4];
#pragma unroll
    for (int m = 0; m < 4; m++) {
      int row = wid * 64 + m * 16 + (lane & 15);
      int c = ks * 4 + (lane >> 4);
      af[m] = *(const f16x8*)(AsB + row * 128 + ((c ^ (row & 7)) << 4));
    }
#pragma unroll
    for (int n = 0; n < 4; n++) {
      int row = n * 16 + (lane & 15);
      int c = ks * 4 + (lane >> 4);
      bf[n] = *(const f16x8*)(BsB + row * 128 + ((c ^ (row & 7)) << 4));
    }
#pragma unroll
    for (int m = 0; m < 4; m++)
#pragma unroll
      for (int n = 0; n < 4; n++)
        acc[m][n] = __builtin_amdgcn_mfma_f32_16x16x32_f16(af[m], bf[n], acc[m][n], 0, 0, 0);
  }
  const int kkm1 = (1 << l2kk) - 1;
#pragma unroll
  for (int n = 0; n < 4; n++) {
    int c = n * 16 + (lane & 15);
    float bj = b2T[tap * 64 + c];
#pragma unroll
    for (int m = 0; m < 4; m++) {
      int rbase = m0 + wid * 64 + m * 16 + (lane >> 4) * 4;
#pragma unroll
      for (int r = 0; r < 4; r++) {
        int row = rbase + r;
        if (row < M) {
          int o = row & 63, g = row >> 6;
          int i = g >> l2kk, jb = g & kkm1;
          wout[((size_t)tap * Cout + (i << 6) + o) * Cin + (jb << 6) + c] =
              (f16)(acc[m][n][r] + bj);
        }
      }
    }
  }
}

// ---------------- MFMA implicit-GEMM conv, 128x128 flagship (r15 form) ----------------
template <int FUSE>
__global__ __launch_bounds__(512) void k_conv_mfma(
    const f16* __restrict__ in, f16* __restrict__ outh, float* __restrict__ outf,
    const f16* __restrict__ wt, float* __restrict__ stats,
    int Cin, int Cout, int Hin, int l2W, int l2HW, int stride, int KS) {
  __shared__ f16 As[128 * 64];
  __shared__ f16 Bs[128 * 64];
  __shared__ float bns[256];

  const int t = threadIdx.x;
  const int lane = t & 63;
  const int wid = t >> 6;
  const int wm = wid >> 2, wn = wid & 3;

  const int gx = gridDim.x;
  const int nwg = gx * gridDim.y;
  const int flat = blockIdx.y * gx + blockIdx.x;
  const int qq = nwg >> 3, rr = nwg & 7;
  const int xcd = flat & 7, ii = flat >> 3;
  const int swz = (xcd < rr ? xcd * (qq + 1) : rr * (qq + 1) + (xcd - rr) * qq) + ii;
  const int m0 = (swz % gx) * 128, co0 = (swz / gx) * 128;

  if (FUSE && t < 256) bns[t] = 0.f;

  const int r0 = t >> 3;
  const int ch = t & 7;
  const f16* abase[2];
  unsigned vmask[2];
  const f16* bbase[2];
#pragma unroll
  for (int q = 0; q < 2; q++) {
    int pix = m0 + r0 + q * 64;
    int pn = pix >> l2HW;
    int prem = pix & ((1 << l2HW) - 1);
    int py = prem >> l2W;
    int px = prem & ((1 << l2W) - 1);
    long py0 = (long)py * stride - 1, px0 = (long)px * stride - 1;
    abase[q] = in + ((long)pn * Hin + py0) * Hin * Cin + px0 * Cin + ch * 8;
    unsigned m = 0;
#pragma unroll
    for (int tt = 0; tt < 9; tt++) {
      int iy = py * stride + tt / 3 - 1;
      int ix = px * stride + tt % 3 - 1;
      if ((unsigned)iy < (unsigned)Hin && (unsigned)ix < (unsigned)Hin) m |= 1u << tt;
    }
    vmask[q] = m;
    bbase[q] = wt + (size_t)(co0 + r0 + q * 64) * Cin + ch * 8;
  }
  const size_t bTap = (size_t)Cout * Cin;

  char* AsB = (char*)As;
  char* BsB = (char*)Bs;
  const int aw0 = r0 * 128 + ((ch ^ (r0 & 7)) << 4);
  const int aw1 = (r0 + 64) * 128 + ((ch ^ (r0 & 7)) << 4);

  int aro[4][2], bro[2][2];
#pragma unroll
  for (int m = 0; m < 4; m++) {
    int row = wm * 64 + m * 16 + (lane & 15);
#pragma unroll
    for (int ks = 0; ks < 2; ks++) {
      int c = ks * 4 + (lane >> 4);
      aro[m][ks] = row * 128 + ((c ^ (row & 7)) << 4);
    }
  }
#pragma unroll
  for (int n = 0; n < 2; n++) {
    int row = wn * 32 + n * 16 + (lane & 15);
#pragma unroll
    for (int ks = 0; ks < 2; ks++) {
      int c = ks * 4 + (lane >> 4);
      bro[n][ks] = row * 128 + ((c ^ (row & 7)) << 4);
    }
  }

  f32x4 acc[4][2];
#pragma unroll
  for (int m = 0; m < 4; m++)
#pragma unroll
    for (int n = 0; n < 2; n++) acc[m][n] = (f32x4){0.f, 0.f, 0.f, 0.f};

  const int ck = Cin >> 6;
  const int S = 9 * ck;
  int sBeg = 0, sEnd = S;
  if (!FUSE) {
    sBeg = (int)(((long)blockIdx.z * S) / KS);
    sEnd = (int)(((long)(blockIdx.z + 1) * S) / KS);
  }
  int tap = sBeg % 9;
  int kin = (sBeg / 9) << 6;

  f16x8 zz = {};
  f16x8 av[2], bv[2];
  {
    const int aoff = ((tap / 3) * Hin + (tap % 3)) * Cin + kin;
    const size_t boff = (size_t)tap * bTap + kin;
#pragma unroll
    for (int q = 0; q < 2; q++) {
      av[q] = ((vmask[q] >> tap) & 1) ? *(const f16x8*)(abase[q] + aoff) : zz;
      bv[q] = *(const f16x8*)(bbase[q] + boff);
    }
  }

  for (int s = sBeg; s < sEnd; s++) {
    __syncthreads();
    *(f16x8*)(AsB + aw0) = av[0];
    *(f16x8*)(AsB + aw1) = av[1];
    *(f16x8*)(BsB + aw0) = bv[0];
    *(f16x8*)(BsB + aw1) = bv[1];
    __syncthreads();
    if (s + 1 < sEnd) {
      tap++;
      if (tap == 9) { tap = 0; kin += 64; }
      const int aoff = ((tap / 3) * Hin + (tap % 3)) * Cin + kin;
      const size_t boff = (size_t)tap * bTap + kin;
#pragma unroll
      for (int q = 0; q < 2; q++) {
        av[q] = ((vmask[q] >> tap) & 1) ? *(const f16x8*)(abase[q] + aoff) : zz;
        bv[q] = *(const f16x8*)(bbase[q] + boff);
      }
    }
#pragma unroll
    for (int ks = 0; ks < 2; ks++) {
      f16x8 af[4], bf[2];
#pragma unroll
      for (int m = 0; m < 4; m++) af[m] = *(const f16x8*)(AsB + aro[m][ks]);
#pragma unroll
      for (int n = 0; n < 2; n++) bf[n] = *(const f16x8*)(BsB + bro[n][ks]);
#pragma unroll
      for (int m = 0; m < 4; m++)
#pragma unroll
        for (int n = 0; n < 2; n++)
          acc[m][n] = __builtin_amdgcn_mfma_f32_16x16x32_f16(af[m], bf[n], acc[m][n], 0, 0, 0);
    }
  }

  const int colL = lane & 15;
  const int rowL = (lane >> 4) * 4;
#pragma unroll
  for (int m = 0; m < 4; m++) {
    int prow = m0 + wm * 64 + m * 16 + rowL;
#pragma unroll
    for (int n = 0; n < 2; n++) {
      int col = co0 + wn * 32 + n * 16 + colL;
      if (col < Cout) {
        if (FUSE) {
#pragma unroll
          for (int r = 0; r < 4; r++)
            outh[(size_t)(prow + r) * Cout + col] = (f16)acc[m][n][r];
        } else {
#pragma unroll
          for (int r = 0; r < 4; r++)
            atomicAdd(&outf[(size_t)(prow + r) * Cout + col], acc[m][n][r]);
        }
      }
    }
  }
  if (FUSE) {
#pragma unroll
    for (int n = 0; n < 2; n++) {
      float s1 = 0.f, s2 = 0.f;
#pragma unroll
      for (int m = 0; m < 4; m++)
#pragma unroll
        for (int r = 0; r < 4; r++) { float v = acc[m][n][r]; s1 += v; s2 += v * v; }
      s1 += __shfl_xor(s1, 16); s2 += __shfl_xor(s2, 16);
      s1 += __shfl_xor(s1, 32); s2 += __shfl_xor(s2, 32);
      if (lane < 16) {
        int c = wn * 32 + n * 16 + colL;
        atomicAdd(&bns[c], s1);
        atomicAdd(&bns[128 + c], s2);
      }
    }
    __syncthreads();
    if (t < 128 && co0 + t < Cout) {
      atomicAdd(&stats[co0 + t], bns[t]);
      atomicAdd(&stats[Cout + co0 + t], bns[128 + t]);
    }
  }
}

// ---------------- small-tile conv (BK=64), used for Cout=64 path: 128x64, 512 thr ----------------
template <int FUSE, int MT, int NT, int NTHR>
__global__ __launch_bounds__(NTHR) void k_conv_s(
    const f16* __restrict__ in, f16* __restrict__ outh, float* __restrict__ outf,
    const f16* __restrict__ wt, float* __restrict__ stats,
    int Cin, int Cout, int Hin, int l2W, int l2HW, int stride, int KS) {
  constexpr int WN = NT / 32;
  constexpr int RP = NTHR / 8;
  constexpr int NA = MT / RP;
  constexpr int NB = NT / RP;
  __shared__ f16 As[MT * 64];
  __shared__ f16 Bs[NT * 64];
  __shared__ float bns[2 * NT];

  const int t = threadIdx.x;
  const int lane = t & 63;
  const int wid = t >> 6;
  const int wm = wid / WN, wn = wid % WN;

  const int gx = gridDim.x;
  const int nwg = gx * gridDim.y;
  const int flat = blockIdx.y * gx + blockIdx.x;
  const int qq = nwg >> 3, rr = nwg & 7;
  const int xcd = flat & 7, ii = flat >> 3;
  const int swz = (xcd < rr ? xcd * (qq + 1) : rr * (qq + 1) + (xcd - rr) * qq) + ii;
  const int m0 = (swz % gx) * MT, co0 = (swz / gx) * NT;

  if (FUSE && t < 2 * NT) bns[t] = 0.f;

  const int r0 = t >> 3;
  const int ch = t & 7;
  const f16* abase[NA];
  unsigned vmask[NA];
  const f16* bbase[NB];
#pragma unroll
  for (int q = 0; q < NA; q++) {
    int pix = m0 + r0 + q * RP;
    int pn = pix >> l2HW;
    int prem = pix & ((1 << l2HW) - 1);
    int py = prem >> l2W;
    int px = prem & ((1 << l2W) - 1);
    long py0 = (long)py * stride - 1, px0 = (long)px * stride - 1;
    abase[q] = in + ((long)pn * Hin + py0) * Hin * Cin + px0 * Cin + ch * 8;
    unsigned m = 0;
#pragma unroll
    for (int tt = 0; tt < 9; tt++) {
      int iy = py * stride + tt / 3 - 1;
      int ix = px * stride + tt % 3 - 1;
      if ((unsigned)iy < (unsigned)Hin && (unsigned)ix < (unsigned)Hin) m |= 1u << tt;
    }
    vmask[q] = m;
  }
#pragma unroll
  for (int q = 0; q < NB; q++)
    bbase[q] = wt + (size_t)(co0 + r0 + q * RP) * Cin + ch * 8;
  const size_t bTap = (size_t)Cout * Cin;

  char* AsB = (char*)As;
  char* BsB = (char*)Bs;
  int awo[NA], bwo[NB];
#pragma unroll
  for (int q = 0; q < NA; q++) {
    int row = r0 + q * RP;
    awo[q] = row * 128 + ((ch ^ (row & 7)) << 4);
  }
#pragma unroll
  for (int q = 0; q < NB; q++) {
    int row = r0 + q * RP;
    bwo[q] = row * 128 + ((ch ^ (row & 7)) << 4);
  }

  int aro[2][2], bro[2][2];
#pragma unroll
  for (int m = 0; m < 2; m++) {
    int row = wm * 32 + m * 16 + (lane & 15);
#pragma unroll
    for (int ks = 0; ks < 2; ks++) {
      int c = ks * 4 + (lane >> 4);
      aro[m][ks] = row * 128 + ((c ^ (row & 7)) << 4);
    }
  }
#pragma unroll
  for (int n = 0; n < 2; n++) {
    int row = wn * 32 + n * 16 + (lane & 15);
#pragma unroll
    for (int ks = 0; ks < 2; ks++) {
      int c = ks * 4 + (lane >> 4);
      bro[n][ks] = row * 128 + ((c ^ (row & 7)) << 4);
    }
  }

  f32x4 acc[2][2];
#pragma unroll
  for (int m = 0; m < 2; m++)
#pragma unroll
    for (int n = 0; n < 2; n++) acc[m][n] = (f32x4){0.f, 0.f, 0.f, 0.f};

  const int ck = Cin >> 6;
  const int S = 9 * ck;
  int sBeg = 0, sEnd = S;
  if (!FUSE) {
    sBeg = (int)(((long)blockIdx.z * S) / KS);
    sEnd = (int)(((long)(blockIdx.z + 1) * S) / KS);
  }
  int tap = sBeg % 9;
  int kin = (sBeg / 9) << 6;

  f16x8 zz = {};
  f16x8 av[NA], bv[NB];
  {
    const int aoff = ((tap / 3) * Hin + (tap % 3)) * Cin + kin;
    const size_t boff = (size_t)tap * bTap + kin;
#pragma unroll
    for (int q = 0; q < NA; q++)
      av[q] = ((vmask[q] >> tap) & 1) ? *(const f16x8*)(abase[q] + aoff) : zz;
#pragma unroll
    for (int q = 0; q < NB; q++) bv[q] = *(const f16x8*)(bbase[q] + boff);
  }

  for (int s = sBeg; s < sEnd; s++) {
    __syncthreads();
#pragma unroll
    for (int q = 0; q < NA; q++) *(f16x8*)(AsB + awo[q]) = av[q];
#pragma unroll
    for (int q = 0; q < NB; q++) *(f16x8*)(BsB + bwo[q]) = bv[q];
    __syncthreads();
    if (s + 1 < sEnd) {
      tap++;
      if (tap == 9) { tap = 0; kin += 64; }
      const int aoff = ((tap / 3) * Hin + (tap % 3)) * Cin + kin;
      const size_t boff = (size_t)tap * bTap + kin;
#pragma unroll
      for (int q = 0; q < NA; q++)
        av[q] = ((vmask[q] >> tap) & 1) ? *(const f16x8*)(abase[q] + aoff) : zz;
#pragma unroll
      for (int q = 0; q < NB; q++) bv[q] = *(const f16x8*)(bbase[q] + boff);
    }
#pragma unroll
    for (int ks = 0; ks < 2; ks++) {
      f16x8 af[2], bf[2];
#pragma unroll
      for (int m = 0; m < 2; m++) af[m] = *(const f16x8*)(AsB + aro[m][ks]);
#pragma unroll
      for (int n = 0; n < 2; n++) bf[n] = *(const f16x8*)(BsB + bro[n][ks]);
#pragma unroll
      for (int m = 0; m < 2; m++)
#pragma unroll
        for (int n = 0; n < 2; n++)
          acc[m][n] = __builtin_amdgcn_mfma_f32_16x16x32_f16(af[m], bf[n], acc[m][n], 0, 0, 0);
    }
  }

  const int colL = lane & 15;
  const int rowL = (lane >> 4) * 4;
#pragma unroll
  for (int m = 0; m < 2; m++) {
    int prow = m0 + wm * 32 + m * 16 + rowL;
#pragma unroll
    for (int n = 0; n < 2; n++) {
      int col = co0 + wn * 32 + n * 16 + colL;
      if (col < Cout) {
        if (FUSE) {
#pragma unroll
          for (int r = 0; r < 4; r++)
            outh[(size_t)(prow + r) * Cout + col] = (f16)acc[m][n][r];
        } else {
#pragma unroll
          for (int r = 0; r < 4; r++)
            atomicAdd(&outf[(size_t)(prow + r) * Cout + col], acc[m][n][r]);
        }
      }
    }
  }
  if (FUSE) {
#pragma unroll
    for (int n = 0; n < 2; n++) {
      float s1 = 0.f, s2 = 0.f;
#pragma unroll
      for (int m = 0; m < 2; m++)
#pragma unroll
        for (int r = 0; r < 4; r++) { float v = acc[m][n][r]; s1 += v; s2 += v * v; }
      s1 += __shfl_xor(s1, 16); s2 += __shfl_xor(s2, 16);
      s1 += __shfl_xor(s1, 32); s2 += __shfl_xor(s2, 32);
      if (lane < 16) {
        int c = wn * 32 + n * 16 + colL;
        atomicAdd(&bns[c], s1);
        atomicAdd(&bns[NT + c], s2);
      }
    }
    __syncthreads();
    if (t < NT && co0 + t < Cout) {
      atomicAdd(&stats[co0 + t], bns[t]);
      atomicAdd(&stats[Cout + co0 + t], bns[NT + t]);
    }
  }
}

// ---------------- 64x64 conv, BK=128 (halved barrier-step count), 256 thr ----------------
// Requires Cin % 128 == 0 (true for all routed convs). LDS [64][128] f16 per operand.
template <int FUSE>
__global__ __launch_bounds__(256) void k_conv_s2(
    const f16* __restrict__ in, f16* __restrict__ outh, float* __restrict__ outf,
    const f16* __restrict__ wt, float* __restrict__ stats,
    int Cin, int Cout, int Hin, int l2W, int l2HW, int stride, int KS) {
  __shared__ f16 As[64 * 128];
  __shared__ f16 Bs[64 * 128];
  __shared__ float bns[128];

  const int t = threadIdx.x;
  const int lane = t & 63;
  const int wid = t >> 6;
  const int wm = wid >> 1, wn = wid & 1;

  const int gx = gridDim.x;
  const int nwg = gx * gridDim.y;
  const int flat = blockIdx.y * gx + blockIdx.x;
  const int qq = nwg >> 3, rr = nwg & 7;
  const int xcd = flat & 7, ii = flat >> 3;
  const int swz = (xcd < rr ? xcd * (qq + 1) : rr * (qq + 1) + (xcd - rr) * qq) + ii;
  const int m0 = (swz % gx) * 64, co0 = (swz / gx) * 64;

  if (FUSE && t < 128) bns[t] = 0.f;

  const int r0 = t >> 3;       // 0..31; rows r0 and r0+32
  const int c0 = t & 7;        // chunk pair {c0, c0+8}
  const f16* abase[2];
  unsigned vmask[2];
  const f16* bbase[2];
#pragma unroll
  for (int q = 0; q < 2; q++) {
    int pix = m0 + r0 + q * 32;
    int pn = pix >> l2HW;
    int prem = pix & ((1 << l2HW) - 1);
    int py = prem >> l2W;
    int px = prem & ((1 << l2W) - 1);
    long py0 = (long)py * stride - 1, px0 = (long)px * stride - 1;
    abase[q] = in + ((long)pn * Hin + py0) * Hin * Cin + px0 * Cin + c0 * 8;
    unsigned m = 0;
#pragma unroll
    for (int tt = 0; tt < 9; tt++) {
      int iy = py * stride + tt / 3 - 1;
      int ix = px * stride + tt % 3 - 1;
      if ((unsigned)iy < (unsigned)Hin && (unsigned)ix < (unsigned)Hin) m |= 1u << tt;
    }
    vmask[q] = m;
    bbase[q] = wt + (size_t)(co0 + r0 + q * 32) * Cin + c0 * 8;
  }
  const size_t bTap = (size_t)Cout * Cin;

  char* AsB = (char*)As;
  char* BsB = (char*)Bs;
  // LDS write offsets: row stride 256B, chunk (c) swizzled by row&7 (affects low 3 bits)
  int wo[2][2];
#pragma unroll
  for (int q = 0; q < 2; q++) {
    int row = r0 + q * 32;
#pragma unroll
    for (int h2 = 0; h2 < 2; h2++)
      wo[q][h2] = row * 256 + (((c0 + h2 * 8) ^ (row & 7)) << 4);
  }

  // fragment read offsets: ks in 0..3, chunk c = ks*4 + (lane>>4) in [0,16)
  int aro[2][4], bro[2][4];
#pragma unroll
  for (int m = 0; m < 2; m++) {
    int row = wm * 32 + m * 16 + (lane & 15);
#pragma unroll
    for (int ks = 0; ks < 4; ks++) {
      int c = ks * 4 + (lane >> 4);
      aro[m][ks] = row * 256 + ((c ^ (row & 7)) << 4);
    }
  }
#pragma unroll
  for (int n = 0; n < 2; n++) {
    int row = wn * 32 + n * 16 + (lane & 15);
#pragma unroll
    for (int ks = 0; ks < 4; ks++) {
      int c = ks * 4 + (lane >> 4);
      bro[n][ks] = row * 256 + ((c ^ (row & 7)) << 4);
    }
  }

  f32x4 acc[2][2];
#pragma unroll
  for (int m = 0; m < 2; m++)
#pragma unroll
    for (int n = 0; n < 2; n++) acc[m][n] = (f32x4){0.f, 0.f, 0.f, 0.f};

  const int ck2 = Cin >> 7;   // 128-ch slices
  const int S = 9 * ck2;
  int sBeg = 0, sEnd = S;
  if (!FUSE) {
    sBeg = (int)(((long)blockIdx.z * S) / KS);
    sEnd = (int)(((long)(blockIdx.z + 1) * S) / KS);
  }
  int tap = sBeg % 9;
  int kin = (sBeg / 9) << 7;

  f16x8 zz = {};
  f16x8 av[2][2], bv[2][2];
  {
    const int aoff = ((tap / 3) * Hin + (tap % 3)) * Cin + kin;
    const size_t boff = (size_t)tap * bTap + kin;
#pragma unroll
    for (int q = 0; q < 2; q++) {
      bool ok = (vmask[q] >> tap) & 1;
#pragma unroll
      for (int h2 = 0; h2 < 2; h2++) {
        av[q][h2] = ok ? *(const f16x8*)(abase[q] + aoff + h2 * 64) : zz;
        bv[q][h2] = *(const f16x8*)(bbase[q] + boff + h2 * 64);
      }
    }
  }

  for (int s = sBeg; s < sEnd; s++) {
    __syncthreads();
#pragma unroll
    for (int q = 0; q < 2; q++)
#pragma unroll
      for (int h2 = 0; h2 < 2; h2++) {
        *(f16x8*)(AsB + wo[q][h2]) = av[q][h2];
        *(f16x8*)(BsB + wo[q][h2]) = bv[q][h2];
      }
    __syncthreads();
    if (s + 1 < sEnd) {
      tap++;
      if (tap == 9) { tap = 0; kin += 128; }
      const int aoff = ((tap / 3) * Hin + (tap % 3)) * Cin + kin;
      const size_t boff = (size_t)tap * bTap + kin;
#pragma unroll
      for (int q = 0; q < 2; q++) {
        bool ok = (vmask[q] >> tap) & 1;
#pragma unroll
        for (int h2 = 0; h2 < 2; h2++) {
          av[q][h2] = ok ? *(const f16x8*)(abase[q] + aoff + h2 * 64) : zz;
          bv[q][h2] = *(const f16x8*)(bbase[q] + boff + h2 * 64);
        }
      }
    }
#pragma unroll
    for (int ks = 0; ks < 4; ks++) {
      f16x8 af[2], bf[2];
#pragma unroll
      for (int m = 0; m < 2; m++) af[m] = *(const f16x8*)(AsB + aro[m][ks]);
#pragma unroll
      for (int n = 0; n < 2; n++) bf[n] = *(const f16x8*)(BsB + bro[n][ks]);
#pragma unroll
      for (int m = 0; m < 2; m++)
#pragma unroll
        for (int n = 0; n < 2; n++)
          acc[m][n] = __builtin_amdgcn_mfma_f32_16x16x32_f16(af[m], bf[n], acc[m][n], 0, 0, 0);
    }
  }

  const int colL = lane & 15;
  const int rowL = (lane >> 4) * 4;
#pragma unroll
  for (int m = 0; m < 2; m++) {
    int prow = m0 + wm * 32 + m * 16 + rowL;
#pragma unroll
    for (int n = 0; n < 2; n++) {
      int col = co0 + wn * 32 + n * 16 + colL;
      if (col < Cout) {
        if (FUSE) {
#pragma unroll
          for (int r = 0; r < 4; r++)
            outh[(size_t)(prow + r) * Cout + col] = (f16)acc[m][n][r];
        } else {
#pragma unroll
          for (int r = 0; r < 4; r++)
            atomicAdd(&outf[(size_t)(prow + r) * Cout + col], acc[m][n][r]);
        }
      }
    }
  }
  if (FUSE) {
#pragma unroll
    for (int n = 0; n < 2; n++) {
      float s1 = 0.f, s2 = 0.f;
#pragma unroll
      for (int m = 0; m < 2; m++)
#pragma unroll
        for (int r = 0; r < 4; r++) { float v = acc[m][n][r]; s1 += v; s2 += v * v; }
      s1 += __shfl_xor(s1, 16); s2 += __shfl_xor(s2, 16);
      s1 += __shfl_xor(s1, 32); s2 += __shfl_xor(s2, 32);
      if (lane < 16) {
        int c = wn * 32 + n * 16 + colL;
        atomicAdd(&bns[c], s1);
        atomicAdd(&bns[64 + c], s2);
      }
    }
    __syncthreads();
    if (t < 64 && co0 + t < Cout) {
      atomicAdd(&stats[co0 + t], bns[t]);
      atomicAdd(&stats[Cout + co0 + t], bns[64 + t]);
    }
  }
}

// ---------------- batchnorm helpers ----------------
template <typename T>
__global__ void k_bnstats_nhwc(const T* __restrict__ t, float* __restrict__ acc,
                               int C, int npix, int pps) {
  int c = blockIdx.y * 64 + (threadIdx.x & 63);
  int pr = threadIdx.x >> 6;
  int p0 = blockIdx.x * pps;
  int pend = min(p0 + pps, npix);
  float s = 0.f, s2 = 0.f;
  for (int p = p0 + pr; p < pend; p += 4) {
    float v = (float)t[(size_t)p * C + c];
    s += v; s2 += v * v;
  }
  __shared__ float sh1[256], sh2[256];
  sh1[threadIdx.x] = s; sh2[threadIdx.x] = s2;
  __syncthreads();
  if (threadIdx.x < 64) {
    s = sh1[threadIdx.x] + sh1[threadIdx.x + 64] + sh1[threadIdx.x + 128] + sh1[threadIdx.x + 192];
    s2 = sh2[threadIdx.x] + sh2[threadIdx.x + 64] + sh2[threadIdx.x + 128] + sh2[threadIdx.x + 192];
    atomicAdd(&acc[c], s);
    atomicAdd(&acc[C + c], s2);
  }
}

// normalize + optional residual-add + optional relu; C power of two
template <typename T>
__global__ void k_bnapply(const T* __restrict__ src, const f16* __restrict__ res,
                          f16* __restrict__ dst, const float* __restrict__ st,
                          int C, float invn, int total8, int relu) {
  int idx = blockIdx.x * TPB + threadIdx.x;
  if (idx >= total8) return;
  size_t base = (size_t)idx * 8;
  int c0 = (int)(base & (size_t)(C - 1));
  float v[8];
  if constexpr (sizeof(T) == 2) {
    f16x8 x = *(const f16x8*)(src + base);
#pragma unroll
    for (int q = 0; q < 8; q++) v[q] = (float)x[q];
  } else {
    f32x4 x0 = *(const f32x4*)(src + base);
    f32x4 x1 = *(const f32x4*)(src + base + 4);
#pragma unroll
    for (int q = 0; q < 4; q++) { v[q] = x0[q]; v[q + 4] = x1[q]; }
  }
  f16x8 rv;
  if (res) rv = *(const f16x8*)(res + base);
  f16x8 o;
#pragma unroll
  for (int q = 0; q < 8; q++) {
    int c = c0 + q;
    float mean = st[c] * invn;
    float var = st[C + c] * invn - mean * mean;
    float f = (v[q] - mean) * rsqrtf(var + 1e-5f);
    if (res) f += (float)rv[q];
    if (relu) f = fmaxf(f, 0.f);
    o[q] = (f16)f;
  }
  *(f16x8*)(dst + base) = o;
}

// ---------------- input BN (NCHW fp32; raw sums via 192 blocks + atomics) ----------------
__global__ void k_bnstats_x(const float* __restrict__ t, float* __restrict__ mvx) {
  int n = blockIdx.x / 3, c = blockIdx.x - 3 * n;
  const float* p = t + ((size_t)n * 3 + c) * 1024;
  float s = 0.f, s2 = 0.f;
  for (int i = threadIdx.x; i < 1024; i += TPB) { float v = p[i]; s += v; s2 += v * v; }
#pragma unroll
  for (int off = 32; off > 0; off >>= 1) { s += __shfl_down(s, off); s2 += __shfl_down(s2, off); }
  __shared__ float sh[8];
  int wid = threadIdx.x >> 6;
  if ((threadIdx.x & 63) == 0) { sh[wid * 2] = s; sh[wid * 2 + 1] = s2; }
  __syncthreads();
  if (threadIdx.x == 0) {
    for (int w = 1; w < TPB / 64; w++) { s += sh[w * 2]; s2 += sh[w * 2 + 1]; }
    atomicAdd(&mvx[c], s);
    atomicAdd(&mvx[4 + c], s2);
  }
}

// finalize from raw sums inside apply (n=65536 elems per channel)
__global__ void k_apply_x(const float* __restrict__ src, f16* __restrict__ dst,
                          const float* __restrict__ mvx, int total) {
  int idx = blockIdx.x * TPB + threadIdx.x;
  if (idx >= total) return;
  int r = idx & 1023;
  int cch = (idx >> 10) % 3;
  int n = idx / 3072;
  const float invn = 1.f / 65536.f;
  float mean = mvx[cch] * invn;
  float var = mvx[4 + cch] * invn - mean * mean;
  float v = (src[idx] - mean) * rsqrtf(var + 1e-5f);
  dst[((size_t)(n * 1024 + r)) * 64 + cch] = (f16)v;
}

// ---------------- pool + final linear (NHWC) ----------------
__global__ void k_poolfc(const f16* __restrict__ in, const float* __restrict__ fw,
                         const float* __restrict__ fb, float* __restrict__ out) {
  __shared__ float pooled[2048];
  __shared__ float red[4];
  int n = blockIdx.x;
  for (int c = threadIdx.x; c < 2048; c += TPB) {
    float s = 0.f;
#pragma unroll
    for (int p = 0; p < 16; p++) s += (float)in[((size_t)n * 16 + p) * 2048 + c];
    pooled[c] = s * (1.f / 16.f);
  }
  __syncthreads();
  for (int kk = 0; kk < 10; kk++) {
    float s = 0.f;
    for (int c = threadIdx.x; c < 2048; c += TPB) s += pooled[c] * fw[kk * 2048 + c];
#pragma unroll
    for (int off = 32; off > 0; off >>= 1) s += __shfl_down(s, off);
    if ((threadIdx.x & 63) == 0) red[threadIdx.x >> 6] = s;
    __syncthreads();
    if (threadIdx.x == 0) out[n * 10 + kk] = red[0] + red[1] + red[2] + red[3] + fb[kk];
    __syncthreads();
  }
}

extern "C" void kernel_launch(void* const* d_in, const int* in_sizes, int n_in,
                              void* d_out, int out_size, void* d_ws, size_t ws_size,
                              hipStream_t stream) {
  static const int ZS_H[52] = {1,1,4,4,1,1,4,1,1,4,2,2,8,8,2,2,8,2,2,8,2,2,8,4,4,16,16,
                               4,4,16,4,4,16,4,4,16,4,4,16,4,4,16,8,8,32,32,8,8,32,8,8,32};
  static const int ZS_K[52] = {1,1,1,1,4,1,1,4,1,1,4,2,2,4,8,2,2,8,2,2,8,2,2,8,4,4,8,
                               16,4,4,16,4,4,16,4,4,16,4,4,16,4,4,16,8,8,16,32,8,8,32,8,8};
  int offz[52];
  { int a = 0; for (int t = 0; t < 52; t++) { offz[t] = a; a += ZS_H[t] * ZS_K[t]; } }

  const float* x     = (const float*)d_in[0];
  const float* c1w   = (const float*)d_in[1];
  const float* z_all = (const float*)d_in[2];
  const float* hw1   = (const float*)d_in[3];
  const float* hb1   = (const float*)d_in[4];
  const float* hw2   = (const float*)d_in[5];
  const float* hb2   = (const float*)d_in[6];
  const float* fw    = (const float*)d_in[7];
  const float* fb    = (const float*)d_in[8];
  float* out = (float*)d_out;

  // ---- workspace layout (~191 MiB) ----
  char* ws = (char*)d_ws;
  size_t pos = 0;
  auto take = [&](size_t b) -> char* { char* p = ws + pos; pos += (b + 255) & ~(size_t)255; return p; };
  f16*   wbuf    = (f16*)take((size_t)512 * 64 * 576 * 2);   // 37.75 MiB
  f16*   hbuf    = (f16*)take((size_t)3268 * 4096 * 2);      // 26.8 MiB
  f16*   A       = (f16*)take((size_t)16777216 * 2);         // 32 MiB
  f16*   B       = (f16*)take((size_t)16777216 * 2);
  f16*   C_      = (f16*)take((size_t)16777216 * 2);
  float* scratch = (float*)take((size_t)16 << 20);           // 16 MiB fp32 split-K acc
  f16*   xn64    = (f16*)take((size_t)64 * 1024 * 64 * 2);   // 8 MiB channel-padded input
  float* mv      = (float*)take(2 * 2048 * 4);
  float* mv2     = (float*)take(2 * 2048 * 4);
  float* mvx     = (float*)take(8 * 4);
  f16*   hw1T    = (f16*)take((size_t)4096 * 64 * 2);
  f16*   hw2T    = (f16*)take((size_t)576 * 64 * 2);
  float* b2T     = (float*)take(576 * 4);
  f16*   stemW   = (f16*)take((size_t)10 * 64 * 64 * 2);
  if (ws_size < pos) return;

  // ---- one-time prep ----
  hipMemsetAsync(xn64, 0, (size_t)64 * 1024 * 64 * 2, stream);
  k_prep_hw1<<<(4096 * 64 + TPB - 1) / TPB, TPB, 0, stream>>>(hw1, hw1T);
  k_prep_hw2<<<(576 * 64 + TPB - 1) / TPB, TPB, 0, stream>>>(hw2, hb2, hw2T, b2T, mv, mvx);
  k_prep_stemw<<<(10 * 64 * 64 + TPB - 1) / TPB, TPB, 0, stream>>>(c1w, stemW);
  k_gen_h_mfma<<<dim3(13, 64), 256, 0, stream>>>(z_all, hw1T, hb1, hbuf, 3268);

  auto genw = [&](int jj, float* st, int Cout) {
    int nr = ZS_H[jj] * ZS_K[jj];
    int CoutW = ZS_H[jj] * 64, CinW = ZS_K[jj] * 64;
    int M = nr * 64;
    int l2kk = __builtin_ctz(ZS_K[jj]);
    k_gen_w<<<dim3((unsigned)((M + 255) / 256), 9), 256, 0, stream>>>(
        hbuf, hw2T, b2T, wbuf, offz[jj] * 64, M, l2kk, CinW, CoutW, st, 2 * Cout);
  };

  // returns true if split-K path (result in fp32 scratch), false if fused (f16 in dst)
  auto conv = [&](const f16* src, f16* dst, int jj, int Cin, int Cout,
                  int Hin, int Hout, int s, float* st) -> bool {
    genw(jj, st, Cout);
    int M = 64 * Hout * Hout;
    int l2W = (Hout == 32) ? 5 : (Hout == 16) ? 4 : (Hout == 8) ? 3 : 2;
    if (Cout == 64) {  // no-waste N=64 path (stage-1 conv1/conv2 + stem)
      k_conv_s<1, 128, 64, 512><<<dim3(M / 128, 1, 1), 512, 0, stream>>>(
          src, dst, nullptr, wbuf, st, Cin, Cout, Hin, l2W, 2 * l2W, s, 1);
      return false;
    }
    int nat128 = (M / 128) * ((Cout + 127) / 128);
    if (nat128 >= 480) {  // big convs: flagship with >=2 blocks/CU
      k_conv_mfma<1><<<dim3(M / 128, (Cout + 127) / 128, 1), 512, 0, stream>>>(
          src, dst, nullptr, wbuf, st, Cin, Cout, Hin, l2W, 2 * l2W, s, 1);
      return false;
    }
    // 64x64 BK=128 path (all such convs have Cin % 128 == 0)
    int nat64 = (M / 64) * (Cout / 64);
    int S2 = 9 * (Cin >> 7);
    if (nat64 >= 480) {
      k_conv_s2<1><<<dim3(M / 64, Cout / 64, 1), 256, 0, stream>>>(
          src, dst, nullptr, wbuf, st, Cin, Cout, Hin, l2W, 2 * l2W, s, 1);
      return false;
    }
    int ks = (480 + nat64 - 1) / nat64;
    if (ks > S2) ks = S2;
    if (ks > 16) ks = 16;
    hipMemsetAsync(scratch, 0, (size_t)M * Cout * 4, stream);
    k_conv_s2<0><<<dim3(M / 64, Cout / 64, ks), 256, 0, stream>>>(
        src, nullptr, scratch, wbuf, nullptr, Cin, Cout, Hin, l2W, 2 * l2W, s, ks);
    dim3 g((unsigned)((M + 63) / 64), (unsigned)(Cout / 64));
    k_bnstats_nhwc<float><<<g, TPB, 0, stream>>>(scratch, st, Cout, M, 64);
    return true;
  };

  auto applyF = [&](bool split, const f16* rawh, const f16* res, f16* dst, float* st,
                    int C, int npix, int relu) {
    int tot8 = npix * C / 8;
    int g = (tot8 + TPB - 1) / TPB;
    if (split)
      k_bnapply<float><<<g, TPB, 0, stream>>>(scratch, res, dst, st, C, 1.f / npix, tot8, relu);
    else
      k_bnapply<f16><<<g, TPB, 0, stream>>>(rawh, res, dst, st, C, 1.f / npix, tot8, relu);
  };

  // ---- data bn: NCHW fp32 -> channel-padded NHWC C=64 fp16 (mvx zeroed in prep) ----
  k_bnstats_x<<<192, TPB, 0, stream>>>(x, mvx);
  { int tot = 64 * 3 * 1024;
    k_apply_x<<<(tot + TPB - 1) / TPB, TPB, 0, stream>>>(x, xn64, mvx, tot); }

  // ---- stem as MFMA conv (Cin=64 padded, Cout=64) + fused stats (mv zeroed in prep) ----
  k_conv_s<1, 128, 64, 512><<<dim3(512, 1, 1), 512, 0, stream>>>(
      xn64, A, nullptr, stemW, mv, 64, 64, 32, 5, 10, 1, 1);
  applyF(false, A, nullptr, A, mv, 64, 64 * 1024, 1);

  // ---- 16 residual blocks ----
  f16* P[3] = {A, B, C_};
  int cur = 0, H = 32, j = 0, cin = 64;
  for (int i = 0; i < 16; i++) {
    bool hasSc = (i == 0 || i == 3 || i == 7 || i == 13);
    int s = (hasSc && i != 0) ? 2 : 1;
    int cmid = ZS_H[j] * 64;
    int cout = ZS_H[j + 2] * 64;
    int Hin = H, Hout = H / s;
    int f1 = (cur + 1) % 3, f2 = (cur + 2) % 3;

    bool c1 = conv(P[cur], P[f1], j, cin, cmid, Hin, Hin, 1, mv);
    applyF(c1, P[f1], nullptr, P[f1], mv, cmid, 64 * Hin * Hin, 1);

    bool c2 = conv(P[f1], P[f2], j + 1, cmid, cmid, Hin, Hout, s, mv);
    applyF(c2, P[f2], nullptr, P[f2], mv, cmid, 64 * Hout * Hout, 1);

    if (hasSc) {
      bool cs = conv(P[cur], P[f1], j + 3, cin, cout, Hin, Hout, s, mv2);
      applyF(cs, P[f1], nullptr, P[f1], mv2, cout, 64 * Hout * Hout, 0);
      bool c3 = conv(P[f2], P[cur], j + 2, cmid, cout, Hout, Hout, 1, mv);
      applyF(c3, P[cur], P[f1], P[cur], mv, cout, 64 * Hout * Hout, 1);
      j += 4;
    } else {
      bool c3 = conv(P[f2], P[f1], j + 2, cmid, cout, Hout, Hout, 1, mv);
      applyF(c3, P[f1], P[cur], P[f2], mv, cout, 64 * Hout * Hout, 1);
      cur = f2;
      j += 3;
    }
    cin = cout; H = Hout;
  }

  // ---- pool + fc ----
  k_poolfc<<<64, TPB, 0, stream>>>(P[cur], fw, fb, out);
}